// Round 1
// baseline (238.386 us; speedup 1.0000x reference)
//
#include <hip/hip_runtime.h>
#include <hip/hip_bf16.h>

#define B_SZ 8192
#define IH   2048
#define H_SZ 1024
#define BM   128
#define BN   32
#define BK   64
#define NT   (IH / BK)   // 32 K-steps

typedef __attribute__((ext_vector_type(8))) short  short8;
typedef __attribute__((ext_vector_type(4))) float  floatx4;

static __device__ __forceinline__ ushort f2bf(float f) {
  union { float f; unsigned u; } v; v.f = f;
  unsigned u = v.u;
  u += 0x7fffu + ((u >> 16) & 1u);   // RNE
  return (ushort)(u >> 16);
}

static __device__ __forceinline__ float sigmoidf_(float x) {
  return 1.0f / (1.0f + __expf(-x));
}
static __device__ __forceinline__ float tanhf_(float x) {
  float ax = fabsf(x);
  float e = __expf(-2.0f * ax);
  float t = (1.0f - e) / (1.0f + e);
  return copysignf(t, x);
}

static __device__ __forceinline__ void gload_lds16(const void* gsrc, void* ldst) {
  __builtin_amdgcn_global_load_lds(
      (__attribute__((address_space(1))) const void*)gsrc,
      (__attribute__((address_space(3))) void*)ldst, 16, 0, 0);
}

// ---------------------------------------------------------------------------
// Pre-pass: W[k][n] fp32 -> Wt[g][n][k] bf16 (K-contiguous for MFMA B-frag)
// ---------------------------------------------------------------------------
__global__ __launch_bounds__(256) void convert_w_kernel(
    const float* __restrict__ Wf, const float* __restrict__ Wi,
    const float* __restrict__ Wo, const float* __restrict__ Wc,
    ushort* __restrict__ Wt) {
  __shared__ float tile[64][65];   // +1 pad: conflict-free column reads
  const int g  = blockIdx.z;
  const float* W = (g == 0) ? Wf : (g == 1) ? Wi : (g == 2) ? Wo : Wc;
  const int n0 = blockIdx.x * 64;
  const int k0 = blockIdx.y * 64;
  const int tid = threadIdx.x;
#pragma unroll
  for (int i = 0; i < 4; ++i) {
    int c = i * 256 + tid;
    int r = c >> 4, c4 = c & 15;
    float4 v = *(const float4*)(W + (size_t)(k0 + r) * H_SZ + n0 + c4 * 4);
    tile[r][c4 * 4 + 0] = v.x;
    tile[r][c4 * 4 + 1] = v.y;
    tile[r][c4 * 4 + 2] = v.z;
    tile[r][c4 * 4 + 3] = v.w;
  }
  __syncthreads();
  const int n  = tid >> 2;
  const int kc = (tid & 3) * 16;
  ushort o[16] __attribute__((aligned(16)));
#pragma unroll
  for (int e = 0; e < 16; ++e) o[e] = f2bf(tile[kc + e][n]);
  ushort* dst = Wt + ((size_t)g * H_SZ + n0 + n) * IH + k0 + kc;
  *(uint4*)(dst)     = *(uint4*)&o[0];
  *(uint4*)(dst + 8) = *(uint4*)&o[8];
}

// ---------------------------------------------------------------------------
// Fused 4-gate GEMM + LSTM epilogue.
// LDS buffer layout (per dbuf half, 32 KiB):
//   [0,      16384): A tile [128 rows][64 k] bf16, XOR-swizzled byte^=(row&7)<<4
//   [16384,  32768): W tile [128 nrt ][64 k] bf16 (nrt = gate*32+n), same swizzle
// ---------------------------------------------------------------------------
__global__ __launch_bounds__(256, 2) void lstm_fused_kernel(
    const float* __restrict__ x,  const float* __restrict__ hp,
    const float* __restrict__ Cp, const ushort* __restrict__ Wt,
    const float* __restrict__ bf_, const float* __restrict__ bi_,
    const float* __restrict__ bo_, const float* __restrict__ bc_,
    float* __restrict__ out) {
  __shared__ char lds[2][32 * 1024];

  // XCD-aware bijective swizzle (2048 % 8 == 0)
  const int bid = blockIdx.x;
  const int wg  = (bid & 7) * (2048 / 8) + (bid >> 3);
  const int b0  = (wg >> 5) * BM;   // 64 row-blocks
  const int n0  = (wg & 31) * BN;   // 32 col-blocks

  const int tid = threadIdx.x;
  const int ln  = tid & 63;
  const int wv  = tid >> 6;

  floatx4 acc[2][8];
#pragma unroll
  for (int i = 0; i < 2; ++i)
#pragma unroll
    for (int j = 0; j < 8; ++j) acc[i][j] = {0.f, 0.f, 0.f, 0.f};

#define STAGE(bufp, k0_)                                                      \
  do {                                                                        \
    char* wb_ = (bufp) + 16384;                                               \
    _Pragma("unroll")                                                         \
    for (int i_ = 0; i_ < 4; ++i_) {                                          \
      int s_   = i_ * 256 + wv * 64 + ln;                                     \
      int nrt_ = s_ >> 3;                                                     \
      int kc_  = s_ & 7;                                                      \
      const char* src_ = (const char*)Wt +                                    \
          (((size_t)(nrt_ >> 5) * H_SZ + n0 + (nrt_ & 31)) * IH + (k0_)) * 2 +\
          ((kc_ * 16) ^ ((nrt_ & 7) << 4));                                   \
      gload_lds16(src_, wb_ + (i_ * 256 + wv * 64) * 16);                     \
    }                                                                         \
    const float* as_ = ((k0_) < 1024)                                         \
        ? x  + (size_t)b0 * 1024 + (k0_)                                      \
        : hp + (size_t)b0 * 1024 + ((k0_) - 1024);                            \
    float4 va_[8];                                                            \
    _Pragma("unroll")                                                         \
    for (int i_ = 0; i_ < 8; ++i_) {                                          \
      int c_ = i_ * 256 + tid;                                                \
      va_[i_] = *(const float4*)(as_ + (size_t)(c_ >> 4) * 1024 + (c_ & 15) * 4); \
    }                                                                         \
    _Pragma("unroll")                                                         \
    for (int i_ = 0; i_ < 8; ++i_) {                                          \
      int c_ = i_ * 256 + tid;                                                \
      int r_ = c_ >> 4, kcc_ = c_ & 15;                                       \
      uint2 t2_;                                                              \
      t2_.x = (unsigned)f2bf(va_[i_].x) | ((unsigned)f2bf(va_[i_].y) << 16);  \
      t2_.y = (unsigned)f2bf(va_[i_].z) | ((unsigned)f2bf(va_[i_].w) << 16);  \
      int byte_ = r_ * 128 + ((kcc_ * 8) ^ ((r_ & 7) << 4));                  \
      *(uint2*)((bufp) + byte_) = t2_;                                        \
    }                                                                         \
  } while (0)

  STAGE(lds[0], 0);
  __syncthreads();

  int bufi = 0;
#pragma unroll 1
  for (int t = 0; t < NT; ++t) {
    char* cur = lds[bufi];
    if (t + 1 < NT) {
      char* nxt = lds[bufi ^ 1];
      STAGE(nxt, (t + 1) * BK);
    }
    char* ab = cur;
    char* wb = cur + 16384;
#pragma unroll
    for (int ks = 0; ks < 2; ++ks) {
      short8 aF[2];
#pragma unroll
      for (int mf = 0; mf < 2; ++mf) {
        int row = wv * 32 + mf * 16 + (ln & 15);
        int kb  = ks * 64 + ((ln >> 4) << 4);
        aF[mf] = *(const short8*)(ab + row * 128 + (kb ^ ((row & 7) << 4)));
      }
#pragma unroll
      for (int j = 0; j < 8; ++j) {
        int nrt = j * 16 + (ln & 15);
        int kb  = ks * 64 + ((ln >> 4) << 4);
        short8 bF = *(const short8*)(wb + nrt * 128 + (kb ^ ((nrt & 7) << 4)));
        acc[0][j] = __builtin_amdgcn_mfma_f32_16x16x32_bf16(aF[0], bF, acc[0][j], 0, 0, 0);
        acc[1][j] = __builtin_amdgcn_mfma_f32_16x16x32_bf16(aF[1], bF, acc[1][j], 0, 0, 0);
      }
    }
    __syncthreads();
    bufi ^= 1;
  }

  // Epilogue: gate g occupies acc[mf][2g + ns]; same lane/reg across gates.
  const int colq = ln & 15;
  const int rq   = ln >> 4;
  float* outh = out;
  float* outC = out + (size_t)B_SZ * H_SZ;
#pragma unroll
  for (int mf = 0; mf < 2; ++mf) {
#pragma unroll
    for (int ns = 0; ns < 2; ++ns) {
      int n = n0 + ns * 16 + colq;
      float vbf = bf_[n], vbi = bi_[n], vbo = bo_[n], vbc = bc_[n];
#pragma unroll
      for (int r = 0; r < 4; ++r) {
        int row = b0 + wv * 32 + mf * 16 + rq * 4 + r;
        float fg = sigmoidf_(acc[mf][0 + ns][r] + vbf);
        float ig = sigmoidf_(acc[mf][2 + ns][r] + vbi);
        float og = sigmoidf_(acc[mf][4 + ns][r] + vbo);
        float cg = tanhf_  (acc[mf][6 + ns][r] + vbc);
        float cp = Cp[(size_t)row * H_SZ + n];
        float Ct = fg * cp + ig * cg;
        float ht = og * tanhf_(Ct);
        outh[(size_t)row * H_SZ + n] = ht;
        outC[(size_t)row * H_SZ + n] = Ct;
      }
    }
  }
#undef STAGE
}

extern "C" void kernel_launch(void* const* d_in, const int* in_sizes, int n_in,
                              void* d_out, int out_size, void* d_ws, size_t ws_size,
                              hipStream_t stream) {
  const float* x  = (const float*)d_in[0];
  const float* hp = (const float*)d_in[1];
  const float* Cp = (const float*)d_in[2];
  const float* Wf = (const float*)d_in[3];
  const float* bf = (const float*)d_in[4];
  const float* Wi = (const float*)d_in[5];
  const float* bi = (const float*)d_in[6];
  const float* Wc = (const float*)d_in[7];
  const float* bc = (const float*)d_in[8];
  const float* Wo = (const float*)d_in[9];
  const float* bo = (const float*)d_in[10];

  ushort* Wt = (ushort*)d_ws;   // bf16 [4][1024][2048] = 16 MiB

  dim3 gridT(16, 32, 4);        // (n-tiles, k-tiles, gates)
  convert_w_kernel<<<gridT, 256, 0, stream>>>(Wf, Wi, Wo, Wc, Wt);

  lstm_fused_kernel<<<2048, 256, 0, stream>>>(x, hp, Cp, Wt,
                                              bf, bi, bo, bc, (float*)d_out);
}

// Round 2
// 182.636 us; speedup vs baseline: 1.3053x; 1.3053x over previous
//
#include <hip/hip_runtime.h>
#include <hip/hip_bf16.h>

#define B_SZ 8192
#define IH   2048
#define H_SZ 1024
#define BM   128
#define BN   32
#define BK   64
#define NT   (IH / BK)   // 32 K-steps

typedef __attribute__((ext_vector_type(8))) short  short8;
typedef __attribute__((ext_vector_type(4))) float  floatx4;

static __device__ __forceinline__ ushort f2bf(float f) {
  union { float f; unsigned u; } v; v.f = f;
  unsigned u = v.u;
  u += 0x7fffu + ((u >> 16) & 1u);   // RNE
  return (ushort)(u >> 16);
}

static __device__ __forceinline__ float sigmoidf_(float x) {
  return 1.0f / (1.0f + __expf(-x));
}
static __device__ __forceinline__ float tanhf_(float x) {
  float ax = fabsf(x);
  float e = __expf(-2.0f * ax);
  float t = (1.0f - e) / (1.0f + e);
  return copysignf(t, x);
}

static __device__ __forceinline__ void gload_lds16(const void* gsrc, void* ldst) {
  __builtin_amdgcn_global_load_lds(
      (__attribute__((address_space(1))) const void*)gsrc,
      (__attribute__((address_space(3))) void*)ldst, 16, 0, 0);
}

// ---------------------------------------------------------------------------
// Pre-pass 1: W[k][n] fp32 -> Wt[g][n][k] bf16 (K-contiguous for MFMA B-frag)
// ---------------------------------------------------------------------------
__global__ __launch_bounds__(256) void convert_w_kernel(
    const float* __restrict__ Wf, const float* __restrict__ Wi,
    const float* __restrict__ Wo, const float* __restrict__ Wc,
    ushort* __restrict__ Wt) {
  __shared__ float tile[64][65];   // +1 pad: conflict-free column reads
  const int g  = blockIdx.z;
  const float* W = (g == 0) ? Wf : (g == 1) ? Wi : (g == 2) ? Wo : Wc;
  const int n0 = blockIdx.x * 64;
  const int k0 = blockIdx.y * 64;
  const int tid = threadIdx.x;
#pragma unroll
  for (int i = 0; i < 4; ++i) {
    int c = i * 256 + tid;
    int r = c >> 4, c4 = c & 15;
    float4 v = *(const float4*)(W + (size_t)(k0 + r) * H_SZ + n0 + c4 * 4);
    tile[r][c4 * 4 + 0] = v.x;
    tile[r][c4 * 4 + 1] = v.y;
    tile[r][c4 * 4 + 2] = v.z;
    tile[r][c4 * 4 + 3] = v.w;
  }
  __syncthreads();
  const int n  = tid >> 2;
  const int kc = (tid & 3) * 16;
  ushort o[16] __attribute__((aligned(16)));
#pragma unroll
  for (int e = 0; e < 16; ++e) o[e] = f2bf(tile[kc + e][n]);
  ushort* dst = Wt + ((size_t)g * H_SZ + n0 + n) * IH + k0 + kc;
  *(uint4*)(dst)     = *(uint4*)&o[0];
  *(uint4*)(dst + 8) = *(uint4*)&o[8];
}

// ---------------------------------------------------------------------------
// Pre-pass 2: A = [x | h_prev] fp32 -> Abf[8192][2048] bf16 (row-major)
// ---------------------------------------------------------------------------
__global__ __launch_bounds__(256) void convert_a_kernel(
    const float* __restrict__ x, const float* __restrict__ hp,
    ushort* __restrict__ Abf) {
  size_t idx = ((size_t)blockIdx.x * 256 + threadIdx.x) * 8;  // 8 elems/thread
  size_t row = idx >> 11;        // / 2048
  size_t col = idx & 2047;       // 1024 % 8 == 0: never straddles x/hp
  const float* src = (col < 1024) ? (x  + row * 1024 + col)
                                  : (hp + row * 1024 + (col - 1024));
  float4 v0 = *(const float4*)(src);
  float4 v1 = *(const float4*)(src + 4);
  ushort o[8] __attribute__((aligned(16)));
  o[0] = f2bf(v0.x); o[1] = f2bf(v0.y); o[2] = f2bf(v0.z); o[3] = f2bf(v0.w);
  o[4] = f2bf(v1.x); o[5] = f2bf(v1.y); o[6] = f2bf(v1.z); o[7] = f2bf(v1.w);
  *(uint4*)(Abf + idx) = *(uint4*)&o[0];
}

// ---------------------------------------------------------------------------
// Fused 4-gate GEMM + LSTM epilogue.
// LDS per dbuf half (32 KiB):
//   [0,     16384): A tile [128 rows][64 k] bf16, swizzle byte^=(row&7)<<4
//   [16384, 32768): W tile [128 nrt ][64 k] bf16 (nrt = gate*32+n), same swizzle
// Both tiles staged via global_load_lds (linear LDS dest, pre-swizzled global
// source — rule #21's BOTH-sides-or-neither pattern).
// PRE=1: A from pre-converted bf16 Abf. PRE=0: fallback reg-staged fp32 A.
// ---------------------------------------------------------------------------
template <int PRE>
__global__ __launch_bounds__(256, 2) void lstm_fused_kernel(
    const float* __restrict__ x,  const float* __restrict__ hp,
    const float* __restrict__ Cp, const ushort* __restrict__ Wt,
    const ushort* __restrict__ Abf,
    const float* __restrict__ bf_, const float* __restrict__ bi_,
    const float* __restrict__ bo_, const float* __restrict__ bc_,
    float* __restrict__ out) {
  __shared__ char lds[2][32 * 1024];

  // XCD-aware bijective swizzle (2048 % 8 == 0)
  const int bid = blockIdx.x;
  const int wg  = (bid & 7) * (2048 / 8) + (bid >> 3);
  const int b0  = (wg >> 5) * BM;   // 64 row-blocks
  const int n0  = (wg & 31) * BN;   // 32 col-blocks

  const int tid = threadIdx.x;
  const int ln  = tid & 63;
  const int wv  = tid >> 6;

  floatx4 acc[2][8];
#pragma unroll
  for (int i = 0; i < 2; ++i)
#pragma unroll
    for (int j = 0; j < 8; ++j) acc[i][j] = {0.f, 0.f, 0.f, 0.f};

  auto stage = [&](char* bufp, int k0_) {
    char* wb = bufp + 16384;
#pragma unroll
    for (int i = 0; i < 4; ++i) {
      int s   = i * 256 + wv * 64 + ln;
      int nrt = s >> 3;
      int kc  = s & 7;
      const char* src = (const char*)Wt +
          (((size_t)(nrt >> 5) * H_SZ + n0 + (nrt & 31)) * IH + k0_) * 2 +
          ((kc * 16) ^ ((nrt & 7) << 4));
      gload_lds16(src, wb + (i * 256 + wv * 64) * 16);
    }
    if constexpr (PRE) {
#pragma unroll
      for (int i = 0; i < 4; ++i) {
        int s  = i * 256 + wv * 64 + ln;
        int r  = s >> 3;
        int kc = s & 7;
        const char* src = (const char*)Abf +
            ((size_t)(b0 + r) * IH + k0_) * 2 + ((kc * 16) ^ ((r & 7) << 4));
        gload_lds16(src, bufp + (i * 256 + wv * 64) * 16);
      }
    } else {
      const float* as_ = (k0_ < 1024)
          ? x  + (size_t)b0 * 1024 + k0_
          : hp + (size_t)b0 * 1024 + (k0_ - 1024);
      float4 va[8];
#pragma unroll
      for (int i = 0; i < 8; ++i) {
        int c = i * 256 + tid;
        va[i] = *(const float4*)(as_ + (size_t)(c >> 4) * 1024 + (c & 15) * 4);
      }
#pragma unroll
      for (int i = 0; i < 8; ++i) {
        int c = i * 256 + tid;
        int r = c >> 4, kcc = c & 15;
        uint2 t2;
        t2.x = (unsigned)f2bf(va[i].x) | ((unsigned)f2bf(va[i].y) << 16);
        t2.y = (unsigned)f2bf(va[i].z) | ((unsigned)f2bf(va[i].w) << 16);
        int byte_ = r * 128 + ((kcc * 8) ^ ((r & 7) << 4));
        *(uint2*)(bufp + byte_) = t2;
      }
    }
  };

  stage(lds[0], 0);
  __syncthreads();

  int bufi = 0;
#pragma unroll 1
  for (int t = 0; t < NT; ++t) {
    char* cur = lds[bufi];
    if (t + 1 < NT) stage(lds[bufi ^ 1], (t + 1) * BK);
    char* ab = cur;
    char* wb = cur + 16384;
#pragma unroll
    for (int ks = 0; ks < 2; ++ks) {
      short8 aF[2];
#pragma unroll
      for (int mf = 0; mf < 2; ++mf) {
        int row = wv * 32 + mf * 16 + (ln & 15);
        int kb  = ks * 64 + ((ln >> 4) << 4);
        aF[mf] = *(const short8*)(ab + row * 128 + (kb ^ ((row & 7) << 4)));
      }
#pragma unroll
      for (int j = 0; j < 8; ++j) {
        int nrt = j * 16 + (ln & 15);
        int kb  = ks * 64 + ((ln >> 4) << 4);
        short8 bF = *(const short8*)(wb + nrt * 128 + (kb ^ ((nrt & 7) << 4)));
        acc[0][j] = __builtin_amdgcn_mfma_f32_16x16x32_bf16(aF[0], bF, acc[0][j], 0, 0, 0);
        acc[1][j] = __builtin_amdgcn_mfma_f32_16x16x32_bf16(aF[1], bF, acc[1][j], 0, 0, 0);
      }
    }
    __syncthreads();
    bufi ^= 1;
  }

  // Epilogue: gate g occupies acc[mf][2g + ns]; same lane/reg across gates.
  const int colq = ln & 15;
  const int rq   = ln >> 4;
  float* outh = out;
  float* outC = out + (size_t)B_SZ * H_SZ;
#pragma unroll
  for (int mf = 0; mf < 2; ++mf) {
#pragma unroll
    for (int ns = 0; ns < 2; ++ns) {
      int n = n0 + ns * 16 + colq;
      float vbf = bf_[n], vbi = bi_[n], vbo = bo_[n], vbc = bc_[n];
#pragma unroll
      for (int r = 0; r < 4; ++r) {
        int row = b0 + wv * 32 + mf * 16 + rq * 4 + r;
        float fg = sigmoidf_(acc[mf][0 + ns][r] + vbf);
        float ig = sigmoidf_(acc[mf][2 + ns][r] + vbi);
        float og = sigmoidf_(acc[mf][4 + ns][r] + vbo);
        float cg = tanhf_  (acc[mf][6 + ns][r] + vbc);
        float cp = Cp[(size_t)row * H_SZ + n];
        float Ct = fg * cp + ig * cg;
        float ht = og * tanhf_(Ct);
        outh[(size_t)row * H_SZ + n] = ht;
        outC[(size_t)row * H_SZ + n] = Ct;
      }
    }
  }
}

extern "C" void kernel_launch(void* const* d_in, const int* in_sizes, int n_in,
                              void* d_out, int out_size, void* d_ws, size_t ws_size,
                              hipStream_t stream) {
  const float* x  = (const float*)d_in[0];
  const float* hp = (const float*)d_in[1];
  const float* Cp = (const float*)d_in[2];
  const float* Wf = (const float*)d_in[3];
  const float* bf = (const float*)d_in[4];
  const float* Wi = (const float*)d_in[5];
  const float* bi = (const float*)d_in[6];
  const float* Wc = (const float*)d_in[7];
  const float* bc = (const float*)d_in[8];
  const float* Wo = (const float*)d_in[9];
  const float* bo = (const float*)d_in[10];

  ushort* Wt  = (ushort*)d_ws;                           // bf16 [4][1024][2048] = 16 MiB
  ushort* Abf = (ushort*)((char*)d_ws + (16u << 20));    // bf16 [8192][2048]   = 32 MiB

  dim3 gridT(16, 32, 4);        // (n-tiles, k-tiles, gates)
  convert_w_kernel<<<gridT, 256, 0, stream>>>(Wf, Wi, Wo, Wc, Wt);

  const bool pre = ws_size >= (48ull << 20);
  if (pre) {
    convert_a_kernel<<<8192, 256, 0, stream>>>(x, hp, Abf);
    lstm_fused_kernel<1><<<2048, 256, 0, stream>>>(x, hp, Cp, Wt, Abf,
                                                   bf, bi, bo, bc, (float*)d_out);
  } else {
    lstm_fused_kernel<0><<<2048, 256, 0, stream>>>(x, hp, Cp, Wt, Abf,
                                                   bf, bi, bo, bc, (float*)d_out);
  }
}

// Round 3
// 177.430 us; speedup vs baseline: 1.3436x; 1.0293x over previous
//
#include <hip/hip_runtime.h>
#include <hip/hip_bf16.h>

#define B_SZ 8192
#define IH   2048
#define H_SZ 1024
#define BM   256          // rows per block
#define BNF  128          // fused cols per block = 4 gates x 32
#define BK   64
#define NT   (IH / BK)    // 32 K-steps
#define ABYTES (BM * BK * 2)            // 32768
#define WBYTES (BNF * BK * 2)           // 16384
#define BUFB   (ABYTES + WBYTES)        // 49152
#define LDS_TOT (3 * BUFB)              // 147456 (<= 160 KiB)

typedef __attribute__((ext_vector_type(8))) short  short8;
typedef __attribute__((ext_vector_type(4))) float  floatx4;

static __device__ __forceinline__ ushort f2bf(float f) {
  union { float f; unsigned u; } v; v.f = f;
  unsigned u = v.u;
  u += 0x7fffu + ((u >> 16) & 1u);   // RNE
  return (ushort)(u >> 16);
}

static __device__ __forceinline__ float sigmoidf_(float x) {
  return 1.0f / (1.0f + __expf(-x));
}
static __device__ __forceinline__ float tanhf_(float x) {
  float ax = fabsf(x);
  float e = __expf(-2.0f * ax);
  float t = (1.0f - e) / (1.0f + e);
  return copysignf(t, x);
}

static __device__ __forceinline__ void gload_lds16(const void* gsrc, void* ldst) {
  __builtin_amdgcn_global_load_lds(
      (__attribute__((address_space(1))) const void*)gsrc,
      (__attribute__((address_space(3))) void*)ldst, 16, 0, 0);
}

// ---------------------------------------------------------------------------
// Pre-pass 1: W[k][n] fp32 -> Wt[g][n][k] bf16 (K-contiguous for MFMA B-frag)
// ---------------------------------------------------------------------------
__global__ __launch_bounds__(256) void convert_w_kernel(
    const float* __restrict__ Wf, const float* __restrict__ Wi,
    const float* __restrict__ Wo, const float* __restrict__ Wc,
    ushort* __restrict__ Wt) {
  __shared__ float tile[64][65];   // +1 pad: conflict-free column reads
  const int g  = blockIdx.z;
  const float* W = (g == 0) ? Wf : (g == 1) ? Wi : (g == 2) ? Wo : Wc;
  const int n0 = blockIdx.x * 64;
  const int k0 = blockIdx.y * 64;
  const int tid = threadIdx.x;
#pragma unroll
  for (int i = 0; i < 4; ++i) {
    int c = i * 256 + tid;
    int r = c >> 4, c4 = c & 15;
    float4 v = *(const float4*)(W + (size_t)(k0 + r) * H_SZ + n0 + c4 * 4);
    tile[r][c4 * 4 + 0] = v.x;
    tile[r][c4 * 4 + 1] = v.y;
    tile[r][c4 * 4 + 2] = v.z;
    tile[r][c4 * 4 + 3] = v.w;
  }
  __syncthreads();
  const int n  = tid >> 2;
  const int kc = (tid & 3) * 16;
  ushort o[16] __attribute__((aligned(16)));
#pragma unroll
  for (int e = 0; e < 16; ++e) o[e] = f2bf(tile[kc + e][n]);
  ushort* dst = Wt + ((size_t)g * H_SZ + n0 + n) * IH + k0 + kc;
  *(uint4*)(dst)     = *(uint4*)&o[0];
  *(uint4*)(dst + 8) = *(uint4*)&o[8];
}

// ---------------------------------------------------------------------------
// Pre-pass 2: A = [x | h_prev] fp32 -> Abf[8192][2048] bf16 (row-major)
// ---------------------------------------------------------------------------
__global__ __launch_bounds__(256) void convert_a_kernel(
    const float* __restrict__ x, const float* __restrict__ hp,
    ushort* __restrict__ Abf) {
  size_t idx = ((size_t)blockIdx.x * 256 + threadIdx.x) * 8;
  size_t row = idx >> 11;
  size_t col = idx & 2047;
  const float* src = (col < 1024) ? (x  + row * 1024 + col)
                                  : (hp + row * 1024 + (col - 1024));
  float4 v0 = *(const float4*)(src);
  float4 v1 = *(const float4*)(src + 4);
  ushort o[8] __attribute__((aligned(16)));
  o[0] = f2bf(v0.x); o[1] = f2bf(v0.y); o[2] = f2bf(v0.z); o[3] = f2bf(v0.w);
  o[4] = f2bf(v1.x); o[5] = f2bf(v1.y); o[6] = f2bf(v1.z); o[7] = f2bf(v1.w);
  *(uint4*)(Abf + idx) = *(uint4*)&o[0];
}

// ---------------------------------------------------------------------------
// Fused 4-gate GEMM + LSTM epilogue. 3-buffer counted-vmcnt pipeline (T3/T4).
//
// LDS buffer b (48 KiB each, 3 buffers):
//   [0,      32768): A tile [256 rows][64 k] bf16, swizzle byte^=(row&7)<<4
//   [32768,  49152): W tile [128 nrt ][64 k] bf16 (nrt = gate*32+n), same swizzle
// Both staged via global_load_lds (linear LDS dest, pre-swizzled global src).
//
// Pipeline ledger (per thread, 6 gload_lds per K-tile):
//   iter t: issue tile t+2 (6 loads) -> compute tile t -> s_waitcnt vmcnt(6)
//   outstanding at the wait = tile(t+2)'s 6 + tile(t+1)'s 6; vmcnt(6) retires
//   exactly tile t+1's loads (issued one full iteration earlier). s_barrier
//   then makes them visible to all waves. Buffer (t+2)%3 was last read in
//   iter t-1, protected by iter t-1's barrier. No full drain in steady state.
// ---------------------------------------------------------------------------
__global__ __launch_bounds__(512, 2) void lstm_fused_kernel(
    const float* __restrict__ Cp, const ushort* __restrict__ Wt,
    const ushort* __restrict__ Abf,
    const float* __restrict__ bf_, const float* __restrict__ bi_,
    const float* __restrict__ bo_, const float* __restrict__ bc_,
    float* __restrict__ out) {
  __shared__ char lds[LDS_TOT];

  // XCD-aware bijective swizzle (1024 % 8 == 0)
  const int bid = blockIdx.x;
  const int wg  = (bid & 7) * 128 + (bid >> 3);
  const int b0  = (wg >> 5) * BM;        // 32 row-tiles
  const int n0g = (wg & 31) * 32;        // 32 col-tiles (per-gate strip of 32)

  const int tid = threadIdx.x;
  const int ln  = tid & 63;
  const int wv  = tid >> 6;              // 8 waves; wave owns rows [wv*32, wv*32+32)

  floatx4 acc[2][8];
#pragma unroll
  for (int i = 0; i < 2; ++i)
#pragma unroll
    for (int j = 0; j < 8; ++j) acc[i][j] = {0.f, 0.f, 0.f, 0.f};

  auto stage = [&](char* bufp, int k0_) {
    // A: 32 KiB = 2048 slots of 16B; 4 per thread
#pragma unroll
    for (int i = 0; i < 4; ++i) {
      int s  = i * 512 + tid;
      int r  = s >> 3;                   // row 0..255
      int kc = s & 7;
      const char* src = (const char*)Abf +
          ((size_t)(b0 + r) * IH + k0_) * 2 + ((kc * 16) ^ ((r & 7) << 4));
      gload_lds16(src, bufp + (i * 512 + wv * 64) * 16);
    }
    // W: 16 KiB = 1024 slots; 2 per thread
    char* wbp = bufp + ABYTES;
#pragma unroll
    for (int i = 0; i < 2; ++i) {
      int s   = i * 512 + tid;
      int nrt = s >> 3;                  // 0..127 (gate*32 + n_local)
      int kc  = s & 7;
      const char* src = (const char*)Wt +
          (((size_t)(nrt >> 5) * H_SZ + n0g + (nrt & 31)) * IH + k0_) * 2 +
          ((kc * 16) ^ ((nrt & 7) << 4));
      gload_lds16(src, wbp + (i * 512 + wv * 64) * 16);
    }
  };

  auto compute_tile = [&](const char* bufp) {
    const char* ab  = bufp;
    const char* wbp = bufp + ABYTES;
#pragma unroll
    for (int ks = 0; ks < 2; ++ks) {
      int kb = ks * 64 + ((ln >> 4) << 4);
      short8 aF[2];
#pragma unroll
      for (int mf = 0; mf < 2; ++mf) {
        int row = wv * 32 + mf * 16 + (ln & 15);
        aF[mf] = *(const short8*)(ab + row * 128 + (kb ^ ((row & 7) << 4)));
      }
#pragma unroll
      for (int j = 0; j < 8; ++j) {
        int nrt = j * 16 + (ln & 15);
        short8 bF = *(const short8*)(wbp + nrt * 128 + (kb ^ ((nrt & 7) << 4)));
        acc[0][j] = __builtin_amdgcn_mfma_f32_16x16x32_bf16(aF[0], bF, acc[0][j], 0, 0, 0);
        acc[1][j] = __builtin_amdgcn_mfma_f32_16x16x32_bf16(aF[1], bF, acc[1][j], 0, 0, 0);
      }
    }
  };

  // ---- prologue: stage tiles 0 and 1; wait for tile 0 (6 newest may fly) ----
  stage(lds + 0 * BUFB, 0 * BK);
  stage(lds + 1 * BUFB, 1 * BK);
  asm volatile("s_waitcnt vmcnt(6)" ::: "memory");
  __builtin_amdgcn_s_barrier();
  __builtin_amdgcn_sched_barrier(0);

  int oc = 0;                 // byte offset of buffer holding tile t
  int os = 2 * BUFB;          // byte offset of buffer for tile t+2
#pragma unroll 1
  for (int t = 0; t < NT - 2; ++t) {
    stage(lds + os, (t + 2) * BK);
    compute_tile(lds + oc);
    asm volatile("s_waitcnt vmcnt(6)" ::: "memory");   // tile t+1 landed
    __builtin_amdgcn_s_barrier();
    __builtin_amdgcn_sched_barrier(0);
    oc += BUFB; if (oc == LDS_TOT) oc = 0;
    os += BUFB; if (os == LDS_TOT) os = 0;
  }
  // t = NT-2: nothing left to stage; drain tile NT-1's loads (issued last iter)
  compute_tile(lds + oc);
  asm volatile("s_waitcnt vmcnt(0)" ::: "memory");
  __builtin_amdgcn_s_barrier();
  __builtin_amdgcn_sched_barrier(0);
  oc += BUFB; if (oc == LDS_TOT) oc = 0;
  // t = NT-1
  compute_tile(lds + oc);

  // ---- epilogue: gate g occupies acc[mf][2g + ns]; same lane/reg across gates
  const int colq = ln & 15;
  const int rq   = ln >> 4;
  float* outh = out;
  float* outC = out + (size_t)B_SZ * H_SZ;
#pragma unroll
  for (int mf = 0; mf < 2; ++mf) {
#pragma unroll
    for (int ns = 0; ns < 2; ++ns) {
      int n = n0g + ns * 16 + colq;
      float vbf = bf_[n], vbi = bi_[n], vbo = bo_[n], vbc = bc_[n];
#pragma unroll
      for (int r = 0; r < 4; ++r) {
        int row = b0 + wv * 32 + mf * 16 + rq * 4 + r;
        float fg = sigmoidf_(acc[mf][0 + ns][r] + vbf);
        float ig = sigmoidf_(acc[mf][2 + ns][r] + vbi);
        float og = sigmoidf_(acc[mf][4 + ns][r] + vbo);
        float cg = tanhf_  (acc[mf][6 + ns][r] + vbc);
        float cp = Cp[(size_t)row * H_SZ + n];
        float Ct = fg * cp + ig * cg;
        float ht = og * tanhf_(Ct);
        outh[(size_t)row * H_SZ + n] = ht;
        outC[(size_t)row * H_SZ + n] = Ct;
      }
    }
  }
}

extern "C" void kernel_launch(void* const* d_in, const int* in_sizes, int n_in,
                              void* d_out, int out_size, void* d_ws, size_t ws_size,
                              hipStream_t stream) {
  const float* x  = (const float*)d_in[0];
  const float* hp = (const float*)d_in[1];
  const float* Cp = (const float*)d_in[2];
  const float* Wf = (const float*)d_in[3];
  const float* bf = (const float*)d_in[4];
  const float* Wi = (const float*)d_in[5];
  const float* bi = (const float*)d_in[6];
  const float* Wc = (const float*)d_in[7];
  const float* bc = (const float*)d_in[8];
  const float* Wo = (const float*)d_in[9];
  const float* bo = (const float*)d_in[10];

  ushort* Wt  = (ushort*)d_ws;                           // bf16 [4][1024][2048] = 16 MiB
  ushort* Abf = (ushort*)((char*)d_ws + (16u << 20));    // bf16 [8192][2048]   = 32 MiB

  dim3 gridT(16, 32, 4);        // (n-tiles, k-tiles, gates)
  convert_w_kernel<<<gridT, 256, 0, stream>>>(Wf, Wi, Wo, Wc, Wt);
  convert_a_kernel<<<8192, 256, 0, stream>>>(x, hp, Abf);

  lstm_fused_kernel<<<1024, 512, 0, stream>>>(Cp, Wt, Abf,
                                              bf, bi, bo, bc, (float*)d_out);
}

// Round 4
// 168.841 us; speedup vs baseline: 1.4119x; 1.0509x over previous
//
#include <hip/hip_runtime.h>
#include <hip/hip_bf16.h>

#define B_SZ 8192
#define IH   2048
#define H_SZ 1024
#define BM   256            // rows per block
#define BK   64             // K per tile
#define NT   (IH / BK)      // 32 K-tiles
#define NI   (NT / 2)       // 16 iterations, 2 K-tiles each
#define DBUF 65536          // one dbuf: A [256][128B] + W [256][128B]
#define WOFF 32768          // W region offset inside a dbuf

typedef __attribute__((ext_vector_type(8))) short  short8;
typedef __attribute__((ext_vector_type(4))) float  floatx4;

static __device__ __forceinline__ ushort f2bf(float f) {
  union { float f; unsigned u; } v; v.f = f;
  unsigned u = v.u;
  u += 0x7fffu + ((u >> 16) & 1u);   // RNE
  return (ushort)(u >> 16);
}
static __device__ __forceinline__ float sigmoidf_(float x) {
  return 1.0f / (1.0f + __expf(-x));
}
static __device__ __forceinline__ float tanhf_(float x) {
  float ax = fabsf(x);
  float e = __expf(-2.0f * ax);
  float t = (1.0f - e) / (1.0f + e);
  return copysignf(t, x);
}
static __device__ __forceinline__ void gload_lds16(const void* gsrc, void* ldst) {
  __builtin_amdgcn_global_load_lds(
      (__attribute__((address_space(1))) const void*)gsrc,
      (__attribute__((address_space(3))) void*)ldst, 16, 0, 0);
}

// ---------------------------------------------------------------------------
// Pre-pass 1: W[k][n] fp32 -> Wt[g][n][k] bf16 (K-contiguous for MFMA B-frag)
// ---------------------------------------------------------------------------
__global__ __launch_bounds__(256) void convert_w_kernel(
    const float* __restrict__ Wf, const float* __restrict__ Wi,
    const float* __restrict__ Wo, const float* __restrict__ Wc,
    ushort* __restrict__ Wt) {
  __shared__ float tile[64][65];
  const int g  = blockIdx.z;
  const float* W = (g == 0) ? Wf : (g == 1) ? Wi : (g == 2) ? Wo : Wc;
  const int n0 = blockIdx.x * 64;
  const int k0 = blockIdx.y * 64;
  const int tid = threadIdx.x;
#pragma unroll
  for (int i = 0; i < 4; ++i) {
    int c = i * 256 + tid;
    int r = c >> 4, c4 = c & 15;
    float4 v = *(const float4*)(W + (size_t)(k0 + r) * H_SZ + n0 + c4 * 4);
    tile[r][c4 * 4 + 0] = v.x;
    tile[r][c4 * 4 + 1] = v.y;
    tile[r][c4 * 4 + 2] = v.z;
    tile[r][c4 * 4 + 3] = v.w;
  }
  __syncthreads();
  const int n  = tid >> 2;
  const int kc = (tid & 3) * 16;
  ushort o[16] __attribute__((aligned(16)));
#pragma unroll
  for (int e = 0; e < 16; ++e) o[e] = f2bf(tile[kc + e][n]);
  ushort* dst = Wt + ((size_t)g * H_SZ + n0 + n) * IH + k0 + kc;
  *(uint4*)(dst)     = *(uint4*)&o[0];
  *(uint4*)(dst + 8) = *(uint4*)&o[8];
}

// ---------------------------------------------------------------------------
// Pre-pass 2: A = [x | h_prev] fp32 -> Abf[8192][2048] bf16
// ---------------------------------------------------------------------------
__global__ __launch_bounds__(256) void convert_a_kernel(
    const float* __restrict__ x, const float* __restrict__ hp,
    ushort* __restrict__ Abf) {
  size_t idx = ((size_t)blockIdx.x * 256 + threadIdx.x) * 8;
  size_t row = idx >> 11;
  size_t col = idx & 2047;
  const float* src = (col < 1024) ? (x  + row * 1024 + col)
                                  : (hp + row * 1024 + (col - 1024));
  float4 v0 = *(const float4*)(src);
  float4 v1 = *(const float4*)(src + 4);
  ushort o[8] __attribute__((aligned(16)));
  o[0] = f2bf(v0.x); o[1] = f2bf(v0.y); o[2] = f2bf(v0.z); o[3] = f2bf(v0.w);
  o[4] = f2bf(v1.x); o[5] = f2bf(v1.y); o[6] = f2bf(v1.z); o[7] = f2bf(v1.w);
  *(uint4*)(Abf + idx) = *(uint4*)&o[0];
}

// ---------------------------------------------------------------------------
// Fused 4-gate GEMM + LSTM epilogue — m201-style 8-phase schedule.
//
// Block tile: 256 rows x (4 gates x 64 cols). 8 waves = 4M x 2N.
// Wave tile: 64 rows (4 mf-frags) x 8 j-frags (j = 2*gate + ns, col =
// gate*64 + wn*32 + ns*16). 64 MFMA / wave / K-tile.
//
// LDS: 2 dbufs x 64 KiB. dbuf d at d*65536: A [256 rows][128 B] then
// W at +32768 [256 nrt][128 B]. Row swizzle byte ^= (row&7)<<4, applied
// on the pre-swizzled global source (write side) and on ds_read (read side).
// Half-tiles: A0=rows 0-127, A1=128-255, W0=nrt 0-127, W1=128-255;
// each = 16 KiB = 2 gload_lds16 / thread.
//
// Iteration i computes K-tiles 2i (dbuf0, phases 1-4) and 2i+1 (dbuf1, 5-8).
// Stage slots (one half-tile per phase; kt wraps &31 in last iterations —
// dead data, identical timing):
//   P1: dbuf1.W1 <- tile 2i+1   (its W0/A0/A1 staged in prev iter P6-P8)
//   P2: dbuf0.W0 <- 2i+2   P3: dbuf0.A0   P4: dbuf0.A1   P5: dbuf0.W1
//   P6: dbuf1.W0 <- 2i+3   P7: dbuf1.A0   P8: dbuf1.A1
// WAR ledger (overwrite >= 1 barrier after last ds_read of that region):
//   W0 read P1/P5 -> staged P2/P6; A read P1-2/P5-6 -> staged P3,P4/P7,P8;
//   W1 read P3/P7 -> staged P5 / next P1.  All hold.
// vmcnt(6) at end of P4: newest 6 = P2,P3,P4 stages may fly => through-P1
//   complete => dbuf1 tile fully landed before P5 reads.  vmcnt(6) at end of
//   P8: newest 6 = P6,P7,P8 => through-P5 complete => dbuf0 ready for next P1.
// Prologue: stage tile0 (4 halves) then tile1 (W0,A0,A1); vmcnt(6) => tile0
//   complete; barrier.  First P1 stages tile1.W1 — matches steady state.
// ---------------------------------------------------------------------------
__global__ __launch_bounds__(512, 2) void lstm_fused_kernel(
    const float* __restrict__ Cp, const ushort* __restrict__ Wt,
    const ushort* __restrict__ Abf,
    const float* __restrict__ bf_, const float* __restrict__ bi_,
    const float* __restrict__ bo_, const float* __restrict__ bc_,
    float* __restrict__ out) {
  __shared__ char lds[2 * DBUF];   // 128 KiB

  const int bid = blockIdx.x;
  const int wg  = (bid & 7) * 64 + (bid >> 3);   // bijective, 512 % 8 == 0
  const int b0  = (wg >> 4) * BM;                // 32 M-tiles
  const int n0g = (wg & 15) * 64;                // 16 N-tiles (64 cols/gate)

  const int tid = threadIdx.x;
  const int ln  = tid & 63;
  const int wv  = tid >> 6;
  const int wm  = wv >> 1, wn = wv & 1;

  floatx4 acc[4][8];
#pragma unroll
  for (int m = 0; m < 4; ++m)
#pragma unroll
    for (int j = 0; j < 8; ++j) acc[m][j] = {0.f, 0.f, 0.f, 0.f};

  // ---- per-thread read constants ----
  const int sw = (ln & 7) << 4;
  int kb[2];
  kb[0] = (((ln >> 4) << 4)) ^ sw;
  kb[1] = (64 + ((ln >> 4) << 4)) ^ sw;
  int arow[4], brow[8];
#pragma unroll
  for (int mf = 0; mf < 4; ++mf)
    arow[mf] = (wm * 64 + mf * 16 + (ln & 15)) * 128;
#pragma unroll
  for (int j = 0; j < 8; ++j) {
    int g = j >> 1, ns = j & 1;
    brow[j] = WOFF + (g * 64 + wn * 32 + ns * 16 + (ln & 15)) * 128;
  }

  // ---- per-thread stage constants ----
  const int    kcsw = ((tid & 7) * 16) ^ (((tid >> 3) & 7) << 4);
  const char*  AbfB = (const char*)Abf;
  const char*  WtB  = (const char*)Wt;
  size_t aoff[2];                 // + (half<<19) + kt*128
#pragma unroll
  for (int i = 0; i < 2; ++i)
    aoff[i] = ((size_t)(b0 + i * 64 + (tid >> 3)) << 12) + kcsw;
  size_t woff[2][2];              // [half][i], + kt*128
#pragma unroll
  for (int h = 0; h < 2; ++h)
#pragma unroll
    for (int i = 0; i < 2; ++i) {
      int nrt  = h * 128 + i * 64 + (tid >> 3);
      int g    = nrt >> 6, nloc = nrt & 63;
      woff[h][i] = ((size_t)(g * H_SZ + n0g + nloc) << 12) + kcsw;
    }
  int dsto[2];
#pragma unroll
  for (int i = 0; i < 2; ++i) dsto[i] = (i * 512 + wv * 64) * 16;

#define STAGE_A(db, ktb, h)                                                   \
  do {                                                                        \
    gload_lds16(AbfB + aoff[0] + ((size_t)(h) << 19) + (ktb),                 \
                lds + (db) + (h) * 16384 + dsto[0]);                          \
    gload_lds16(AbfB + aoff[1] + ((size_t)(h) << 19) + (ktb),                 \
                lds + (db) + (h) * 16384 + dsto[1]);                          \
  } while (0)
#define STAGE_W(db, ktb, h)                                                   \
  do {                                                                        \
    gload_lds16(WtB + woff[h][0] + (ktb),                                     \
                lds + (db) + WOFF + (h) * 16384 + dsto[0]);                   \
    gload_lds16(WtB + woff[h][1] + (ktb),                                     \
                lds + (db) + WOFF + (h) * 16384 + dsto[1]);                   \
  } while (0)

  short8 aF[4][2];
  short8 bF[8][2];
#define RD_A(db, mf)                                                          \
  do {                                                                        \
    aF[mf][0] = *(const short8*)(lds + (db) + arow[mf] + kb[0]);              \
    aF[mf][1] = *(const short8*)(lds + (db) + arow[mf] + kb[1]);              \
  } while (0)
#define RD_B(db, j)                                                           \
  do {                                                                        \
    bF[j][0] = *(const short8*)(lds + (db) + brow[j] + kb[0]);                \
    bF[j][1] = *(const short8*)(lds + (db) + brow[j] + kb[1]);                \
  } while (0)
#define MFQ(mh, jh)                                                           \
  do {                                                                        \
    __builtin_amdgcn_s_setprio(1);                                            \
    _Pragma("unroll")                                                         \
    for (int mf_ = 2 * (mh); mf_ < 2 * (mh) + 2; ++mf_)                       \
      _Pragma("unroll")                                                       \
      for (int j_ = 4 * (jh); j_ < 4 * (jh) + 4; ++j_) {                      \
        acc[mf_][j_] = __builtin_amdgcn_mfma_f32_16x16x32_bf16(               \
            aF[mf_][0], bF[j_][0], acc[mf_][j_], 0, 0, 0);                    \
        acc[mf_][j_] = __builtin_amdgcn_mfma_f32_16x16x32_bf16(               \
            aF[mf_][1], bF[j_][1], acc[mf_][j_], 0, 0, 0);                    \
      }                                                                       \
    __builtin_amdgcn_s_setprio(0);                                            \
  } while (0)
#define BAR   __builtin_amdgcn_s_barrier()
#define LGKM0                                                                 \
  do {                                                                        \
    asm volatile("s_waitcnt lgkmcnt(0)" ::: "memory");                        \
    __builtin_amdgcn_sched_barrier(0);                                        \
  } while (0)
#define VMC6  asm volatile("s_waitcnt vmcnt(6)" ::: "memory")

  // ---- prologue ----
  STAGE_W(0, 0, 0); STAGE_A(0, 0, 0); STAGE_A(0, 0, 1); STAGE_W(0, 0, 1);
  STAGE_W(DBUF, 128, 0); STAGE_A(DBUF, 128, 0); STAGE_A(DBUF, 128, 1);
  VMC6;
  BAR;

#pragma unroll 1
  for (int it = 0; it < NI; ++it) {
    const int kt1b  = (2 * it + 1) * 128;
    const int ktn0b = ((2 * it + 2) & 31) * 128;
    const int ktn1b = ((2 * it + 3) & 31) * 128;
    // P1
    RD_A(0, 0); RD_A(0, 1);
    RD_B(0, 0); RD_B(0, 1); RD_B(0, 2); RD_B(0, 3);
    STAGE_W(DBUF, kt1b, 1);
    BAR; LGKM0; MFQ(0, 0); BAR;
    // P2
    RD_A(0, 2); RD_A(0, 3);
    STAGE_W(0, ktn0b, 0);
    BAR; LGKM0; MFQ(1, 0); BAR;
    // P3
    RD_B(0, 4); RD_B(0, 5); RD_B(0, 6); RD_B(0, 7);
    STAGE_A(0, ktn0b, 0);
    BAR; LGKM0; MFQ(0, 1); BAR;
    // P4
    STAGE_A(0, ktn0b, 1);
    BAR; LGKM0; MFQ(1, 1);
    VMC6; BAR;
    // P5
    RD_A(DBUF, 0); RD_A(DBUF, 1);
    RD_B(DBUF, 0); RD_B(DBUF, 1); RD_B(DBUF, 2); RD_B(DBUF, 3);
    STAGE_W(0, ktn0b, 1);
    BAR; LGKM0; MFQ(0, 0); BAR;
    // P6
    RD_A(DBUF, 2); RD_A(DBUF, 3);
    STAGE_W(DBUF, ktn1b, 0);
    BAR; LGKM0; MFQ(1, 0); BAR;
    // P7
    RD_B(DBUF, 4); RD_B(DBUF, 5); RD_B(DBUF, 6); RD_B(DBUF, 7);
    STAGE_A(DBUF, ktn1b, 0);
    BAR; LGKM0; MFQ(0, 1); BAR;
    // P8
    STAGE_A(DBUF, ktn1b, 1);
    BAR; LGKM0; MFQ(1, 1);
    VMC6; BAR;
  }

  // ---- epilogue: gate g at acc[mf][2g+ns]; same lane/reg across gates ----
  const int colq = ln & 15;
  const int rq   = ln >> 4;
  float* outh = out;
  float* outC = out + (size_t)B_SZ * H_SZ;
#pragma unroll
  for (int mf = 0; mf < 4; ++mf) {
#pragma unroll
    for (int ns = 0; ns < 2; ++ns) {
      int n = n0g + wn * 32 + ns * 16 + colq;
      float vbf = bf_[n], vbi = bi_[n], vbo = bo_[n], vbc = bc_[n];
#pragma unroll
      for (int r = 0; r < 4; ++r) {
        int row = b0 + wm * 64 + mf * 16 + rq * 4 + r;
        float fg = sigmoidf_(acc[mf][0 + ns][r] + vbf);
        float ig = sigmoidf_(acc[mf][2 + ns][r] + vbi);
        float og = sigmoidf_(acc[mf][4 + ns][r] + vbo);
        float cg = tanhf_  (acc[mf][6 + ns][r] + vbc);
        float cp = Cp[(size_t)row * H_SZ + n];
        float Ct = fg * cp + ig * cg;
        float ht = og * tanhf_(Ct);
        outh[(size_t)row * H_SZ + n] = ht;
        outC[(size_t)row * H_SZ + n] = Ct;
      }
    }
  }
#undef STAGE_A
#undef STAGE_W
#undef RD_A
#undef RD_B
#undef MFQ
#undef BAR
#undef LGKM0
#undef VMC6
}

extern "C" void kernel_launch(void* const* d_in, const int* in_sizes, int n_in,
                              void* d_out, int out_size, void* d_ws, size_t ws_size,
                              hipStream_t stream) {
  const float* x  = (const float*)d_in[0];
  const float* hp = (const float*)d_in[1];
  const float* Cp = (const float*)d_in[2];
  const float* Wf = (const float*)d_in[3];
  const float* bf = (const float*)d_in[4];
  const float* Wi = (const float*)d_in[5];
  const float* bi = (const float*)d_in[6];
  const float* Wc = (const float*)d_in[7];
  const float* bc = (const float*)d_in[8];
  const float* Wo = (const float*)d_in[9];
  const float* bo = (const float*)d_in[10];

  ushort* Wt  = (ushort*)d_ws;                           // 16 MiB
  ushort* Abf = (ushort*)((char*)d_ws + (16u << 20));    // 32 MiB

  dim3 gridT(16, 32, 4);
  convert_w_kernel<<<gridT, 256, 0, stream>>>(Wf, Wi, Wo, Wc, Wt);
  convert_a_kernel<<<8192, 256, 0, stream>>>(x, hp, Abf);

  lstm_fused_kernel<<<512, 512, 0, stream>>>(Cp, Wt, Abf,
                                             bf, bi, bo, bc, (float*)d_out);
}